// Round 6
// baseline (26.576 us; speedup 1.0000x reference)
//
#include <hip/hip_runtime.h>

#define S 128
#define B 64
#define W 32
#define D2 512
#define DH 512

typedef float floatx4 __attribute__((ext_vector_type(4)));

// d_out layout (floats), concatenated in reference return order
#define OFF_SEN 0
#define OFF_SWH (B * S)                      // 8192
#define OFF_INITH (OFF_SWH + B * S * D2)     // 4202496
#define OFF_CV (OFF_INITH + B * DH)          // 4235264
#define OFF_LOSS (OFF_CV + B * D2)           // 4268032

// ws control block (16 bytes at byte offset 512, zeroed by memset node each call):
//   [0] unsigned counter, [1] pad, [2] float sum_nll_masked, [3] float sum_cnt
#define WS_CTL_BYTE_OFF 512

// grid partition for the fused kernel
#define NB_BETA 64
#define NB_INITH 128
#define NB_GATHER 2048
#define NB_TOTAL (NB_BETA + NB_INITH + NB_GATHER)

// Single fused kernel:
//  blocks [0,64):        beta dot + log-softmax -> atomic loss contribution; cv copy
//                        last-arriving beta block finalizes the loss (2 atomic reads)
//  blocks [64,192):      init_h (cv recomputed from h_n1 -> no intra-kernel dep)
//  blocks [192,2240):    selected_wiki_h gather (nontemporal float4) + sen cast
__global__ __launch_bounds__(256) void k_fused(
    const float* __restrict__ h1, const float* __restrict__ h_n1,
    const float* __restrict__ h_n, const float* __restrict__ Wi,
    const float* __restrict__ bi, const int* __restrict__ wiki_sen,
    const int* __restrict__ valid_sen, const int* __restrict__ atten_label,
    float* __restrict__ out, float* __restrict__ ws)
{
    __shared__ float smem[4 * 2 * D2];       // 16 KB (inith); others reuse prefix
    const int bid = blockIdx.x;
    const int tid = threadIdx.x;

    if (bid < NB_BETA) {
        // ---- beta / nll / cv / last-block loss finalize ----
        const int b = bid;
        const int lane = tid & 63;
        const int wv = tid >> 6;             // 4 waves
        const int vs = valid_sen[b];
        const int lbl = atten_label[vs];
        float* sbeta = smem;

        const float* hb = h_n + b * D2;
        const float4 hn0 = ((const float4*)hb)[lane];
        const float4 hn1 = ((const float4*)hb)[64 + lane];

        #pragma unroll
        for (int i = 0; i < 8; ++i) {
            const int w = wv * 8 + i;
            const float* row = h_n1 + (w * B + vs) * D2;
            const float4 a0 = ((const float4*)row)[lane];
            const float4 a1 = ((const float4*)row)[64 + lane];
            float p = a0.x * hn0.x + a0.y * hn0.y + a0.z * hn0.z + a0.w * hn0.w
                    + a1.x * hn1.x + a1.y * hn1.y + a1.z * hn1.z + a1.w * hn1.w;
            #pragma unroll
            for (int m = 32; m >= 1; m >>= 1) p += __shfl_xor(p, m);
            if (lane == 0) sbeta[w] = p;
        }

        // wiki_cv[b,:] = h_n1[lbl, vs, :]
        if (tid < 128) {
            const float4* src = (const float4*)(h_n1 + (lbl * B + vs) * D2);
            float4* dst = (float4*)(out + OFF_CV + b * D2);
            dst[tid] = src[tid];
        }
        __syncthreads();

        if (tid == 0) {
            float mx = sbeta[0];
            for (int w = 1; w < W; ++w) mx = fmaxf(mx, sbeta[w]);
            float Z = 0.0f;
            for (int w = 0; w < W; ++w) Z += expf(sbeta[w] - mx);
            const float nll = -(sbeta[lbl] - mx - logf(Z));
            const float vmask = (lbl != 0) ? 1.0f : 0.0f;

            unsigned* ctl = (unsigned*)((char*)ws + WS_CTL_BYTE_OFF);
            float* sums = (float*)(ctl + 2);
            atomicAdd(&sums[0], vmask * nll);
            atomicAdd(&sums[1], vmask);
            __threadfence();
            const unsigned old = atomicAdd(ctl, 1u);
            if (old == NB_BETA - 1) {        // all 64 contributions are in
                __threadfence();
                const float sn = atomicAdd(&sums[0], 0.0f);
                const float sc = atomicAdd(&sums[1], 0.0f);
                out[OFF_LOSS] = (sc > 0.0f) ? sn / fmaxf(sc, 1.0f) : 0.0f;
            }
        }
    } else if (bid < NB_BETA + NB_INITH) {
        // ---- init_h ----
        float (*wrow)[2 * D2] = (float (*)[2 * D2])smem;
        const int kt = (bid - NB_BETA) * 4;

        #pragma unroll
        for (int kk = 0; kk < 4; ++kk) {
            ((float4*)wrow[kk])[tid] =
                ((const float4*)(Wi + (size_t)(kt + kk) * (2 * D2)))[tid];
        }
        __syncthreads();

        const int b = tid >> 2;
        const int kk = tid & 3;
        const int k = kt + kk;
        const int vs = valid_sen[b];
        const int lbl = atten_label[vs];
        float acc = bi[k];
        const float4* hb = (const float4*)(h_n + b * D2);
        const float4* cb = (const float4*)(h_n1 + (lbl * B + vs) * D2);
        const float4* w0 = (const float4*)wrow[kk];
        const float4* w1 = (const float4*)(wrow[kk] + D2);
        #pragma unroll 4
        for (int d = 0; d < D2 / 4; ++d) {
            const float4 a = hb[d], w = w0[d];
            acc += a.x * w.x + a.y * w.y + a.z * w.z + a.w * w.w;
        }
        #pragma unroll 4
        for (int d = 0; d < D2 / 4; ++d) {
            const float4 a = cb[d], w = w1[d];
            acc += a.x * w.x + a.y * w.y + a.z * w.z + a.w * w.w;
        }
        out[OFF_INITH + b * DH + k] = acc;
    } else {
        // ---- selected_wiki_h gather + sen cast (pure streaming, no reuse) ----
        int* gi = (int*)smem;                // gi[b] = vs*W + lbl (row index)
        if (tid < B) {
            const int vs = valid_sen[tid];
            gi[tid] = vs * W + atten_label[vs];
        }
        __syncthreads();

        const int gid = (bid - NB_BETA - NB_INITH) * 256 + tid;  // < 524288

        if (gid < B * S) {
            const int b = gid >> 7, s = gid & 127;
            out[OFF_SEN + gid] = (float)wiki_sen[gi[b] * S + s];
        }

        #pragma unroll
        for (int it = 0; it < 2; ++it) {
            const int q = gid + it * (NB_GATHER * 256);   // float4 index
            const int d4 = q & 127;          // D2/4 = 128
            const int t = q >> 7;
            const int s = t & 127;           // S
            const int b = t >> 7;
            const floatx4* src =
                (const floatx4*)(h1 + ((size_t)(s * (B * W) + gi[b])) * D2);
            const floatx4 v = __builtin_nontemporal_load(&src[d4]);
            __builtin_nontemporal_store(v, &((floatx4*)(out + OFF_SWH))[q]);
        }
    }
}

extern "C" void kernel_launch(void* const* d_in, const int* in_sizes, int n_in,
                              void* d_out, int out_size, void* d_ws, size_t ws_size,
                              hipStream_t stream) {
    // input order: i, valid_sen, reverse_valid_sen, wiki_sen, wiki_num,
    //              h1, h_n1, atten_label, h, h_n, W_init, b_init
    const int* valid_sen   = (const int*)d_in[1];
    const int* wiki_sen    = (const int*)d_in[3];
    const float* h1        = (const float*)d_in[5];
    const float* h_n1      = (const float*)d_in[6];
    const int* atten_label = (const int*)d_in[7];
    const float* h_n       = (const float*)d_in[9];
    const float* Wi        = (const float*)d_in[10];
    const float* bi        = (const float*)d_in[11];
    float* out = (float*)d_out;
    float* ws  = (float*)d_ws;

    // zero the loss control block (counter + accumulators); graph-legal node
    hipMemsetAsync((char*)d_ws + WS_CTL_BYTE_OFF, 0, 16, stream);

    k_fused<<<NB_TOTAL, 256, 0, stream>>>(h1, h_n1, h_n, Wi, bi, wiki_sen,
                                          valid_sen, atten_label, out, ws);
}

// Round 7
// 21.886 us; speedup vs baseline: 1.2143x; 1.2143x over previous
//
#include <hip/hip_runtime.h>

#define S 128
#define B 64
#define W 32
#define D2 512
#define DH 512

typedef float floatx4 __attribute__((ext_vector_type(4)));

// d_out layout (floats), concatenated in reference return order
#define OFF_SEN 0
#define OFF_SWH (B * S)                      // 8192
#define OFF_INITH (OFF_SWH + B * S * D2)     // 4202496
#define OFF_CV (OFF_INITH + B * DH)          // 4235264
#define OFF_LOSS (OFF_CV + B * D2)           // 4268032

// grid partition for the fused kernel
#define NB_BETA 64
#define NB_INITH 128
#define NB_GATHER 1024
#define NB_TOTAL (NB_BETA + NB_INITH + NB_GATHER)

// Fused kernel:
//  blocks [0,64):        beta dot + log-softmax -> nll/valid into ws; cv copy
//  blocks [64,192):      init_h (cv recomputed from h_n1 -> no intra-kernel dep)
//  blocks [192,1216):    selected_wiki_h gather: block-uniform b, 4 independent
//                        nt-loads then 4 nt-stores per thread (MLP), + sen cast
__global__ __launch_bounds__(256) void k_fused(
    const float* __restrict__ h1, const float* __restrict__ h_n1,
    const float* __restrict__ h_n, const float* __restrict__ Wi,
    const float* __restrict__ bi, const int* __restrict__ wiki_sen,
    const int* __restrict__ valid_sen, const int* __restrict__ atten_label,
    float* __restrict__ out, float* __restrict__ ws)
{
    __shared__ float smem[4 * 2 * D2];       // 16 KB (inith); beta uses prefix
    const int bid = blockIdx.x;
    const int tid = threadIdx.x;

    if (bid < NB_BETA) {
        // ---- beta / nll / cv ----
        const int b = bid;
        const int lane = tid & 63;
        const int wv = tid >> 6;             // 4 waves
        const int vs = valid_sen[b];
        const int lbl = atten_label[vs];
        float* sbeta = smem;

        const float* hb = h_n + b * D2;
        const float4 hn0 = ((const float4*)hb)[lane];
        const float4 hn1 = ((const float4*)hb)[64 + lane];

        #pragma unroll
        for (int i = 0; i < 8; ++i) {
            const int w = wv * 8 + i;
            const float* row = h_n1 + (w * B + vs) * D2;
            const float4 a0 = ((const float4*)row)[lane];
            const float4 a1 = ((const float4*)row)[64 + lane];
            float p = a0.x * hn0.x + a0.y * hn0.y + a0.z * hn0.z + a0.w * hn0.w
                    + a1.x * hn1.x + a1.y * hn1.y + a1.z * hn1.z + a1.w * hn1.w;
            #pragma unroll
            for (int m = 32; m >= 1; m >>= 1) p += __shfl_xor(p, m);
            if (lane == 0) sbeta[w] = p;
        }

        // wiki_cv[b,:] = h_n1[lbl, vs, :]
        if (tid < 128) {
            const float4* src = (const float4*)(h_n1 + (lbl * B + vs) * D2);
            float4* dst = (float4*)(out + OFF_CV + b * D2);
            dst[tid] = src[tid];
        }
        __syncthreads();

        if (tid == 0) {
            float mx = sbeta[0];
            for (int w = 1; w < W; ++w) mx = fmaxf(mx, sbeta[w]);
            float Z = 0.0f;
            for (int w = 0; w < W; ++w) Z += expf(sbeta[w] - mx);
            const float nll = -(sbeta[lbl] - mx - logf(Z));
            ws[b] = nll;
            ws[B + b] = (lbl != 0) ? 1.0f : 0.0f;
        }
    } else if (bid < NB_BETA + NB_INITH) {
        // ---- init_h ----
        float (*wrow)[2 * D2] = (float (*)[2 * D2])smem;
        const int kt = (bid - NB_BETA) * 4;

        #pragma unroll
        for (int kk = 0; kk < 4; ++kk) {
            ((float4*)wrow[kk])[tid] =
                ((const float4*)(Wi + (size_t)(kt + kk) * (2 * D2)))[tid];
        }
        __syncthreads();

        const int b = tid >> 2;
        const int kk = tid & 3;
        const int k = kt + kk;
        const int vs = valid_sen[b];
        const int lbl = atten_label[vs];
        float acc = bi[k];
        const float4* hb = (const float4*)(h_n + b * D2);
        const float4* cb = (const float4*)(h_n1 + (lbl * B + vs) * D2);
        const float4* w0 = (const float4*)wrow[kk];
        const float4* w1 = (const float4*)(wrow[kk] + D2);
        #pragma unroll 4
        for (int d = 0; d < D2 / 4; ++d) {
            const float4 a = hb[d], w = w0[d];
            acc += a.x * w.x + a.y * w.y + a.z * w.z + a.w * w.w;
        }
        #pragma unroll 4
        for (int d = 0; d < D2 / 4; ++d) {
            const float4 a = cb[d], w = w1[d];
            acc += a.x * w.x + a.y * w.y + a.z * w.z + a.w * w.w;
        }
        out[OFF_INITH + b * DH + k] = acc;
    } else {
        // ---- selected_wiki_h gather + sen cast ----
        const int gb = bid - NB_BETA - NB_INITH;          // 0..1023
        // block covers float4 indices [gb*1024, gb*1024+1024) = 8 rows, ONE b
        const int b = gb >> 4;                            // (gb*8)>>7
        const int vs = valid_sen[b];                      // wave-uniform -> scalar
        const int gi = vs * W + atten_label[vs];          // h1 row index (b fixed)

        // sen cast: first 32 gather blocks
        const int gid = gb * 256 + tid;
        if (gid < B * S) {
            const int sb = gid >> 7, ss = gid & 127;
            const int svs = valid_sen[sb];
            out[OFF_SEN + gid] = (float)wiki_sen[(svs * W + atten_label[svs]) * S + ss];
        }

        // 4 independent nt-loads, then 4 nt-stores
        floatx4 v[4];
        int q[4];
        #pragma unroll
        for (int j = 0; j < 4; ++j) {
            q[j] = gb * 1024 + j * 256 + tid;             // float4 index
            const int t = q[j] >> 7;                      // row (b,s)
            const int s = t & 127;
            const int d4 = q[j] & 127;
            const floatx4* src =
                (const floatx4*)(h1 + ((size_t)(s * (B * W) + gi)) * D2);
            v[j] = __builtin_nontemporal_load(&src[d4]);
        }
        #pragma unroll
        for (int j = 0; j < 4; ++j) {
            __builtin_nontemporal_store(v[j], &((floatx4*)(out + OFF_SWH))[q[j]]);
        }
    }
}

// Deterministic masked-mean over B=64 values (one wave). Kernel-boundary
// ordering makes ws visible; no atomics needed.
__global__ void k_loss(const float* __restrict__ ws, float* __restrict__ out)
{
    const int t = threadIdx.x;               // 64 threads
    float nll = ws[t];
    float v = ws[B + t];
    float sn = v * nll;
    float sc = v;
    #pragma unroll
    for (int m = 32; m >= 1; m >>= 1) {
        sn += __shfl_xor(sn, m);
        sc += __shfl_xor(sc, m);
    }
    if (t == 0) out[OFF_LOSS] = (sc > 0.0f) ? sn / fmaxf(sc, 1.0f) : 0.0f;
}

extern "C" void kernel_launch(void* const* d_in, const int* in_sizes, int n_in,
                              void* d_out, int out_size, void* d_ws, size_t ws_size,
                              hipStream_t stream) {
    // input order: i, valid_sen, reverse_valid_sen, wiki_sen, wiki_num,
    //              h1, h_n1, atten_label, h, h_n, W_init, b_init
    const int* valid_sen   = (const int*)d_in[1];
    const int* wiki_sen    = (const int*)d_in[3];
    const float* h1        = (const float*)d_in[5];
    const float* h_n1      = (const float*)d_in[6];
    const int* atten_label = (const int*)d_in[7];
    const float* h_n       = (const float*)d_in[9];
    const float* Wi        = (const float*)d_in[10];
    const float* bi        = (const float*)d_in[11];
    float* out = (float*)d_out;
    float* ws  = (float*)d_ws;

    k_fused<<<NB_TOTAL, 256, 0, stream>>>(h1, h_n1, h_n, Wi, bi, wiki_sen,
                                          valid_sen, atten_label, out, ws);
    k_loss<<<1, 64, 0, stream>>>(ws, out);
}